// Round 15
// baseline (195.599 us; speedup 1.0000x reference)
//
#include <hip/hip_runtime.h>

#define HID 64
#define TT  128
#define NROWS 8192
#define NBLK 256            // 256 blocks = 1/CU; each owns TWO 16-row groups
#define LOG2E 1.44269504088896f

typedef _Float16 half8 __attribute__((ext_vector_type(8)));
typedef float    f32x4 __attribute__((ext_vector_type(4)));

// Single-dispatch GRU, 2 independent row-groups per block: each barrier
// interval carries two row-group steps whose dependency chains overlap
// in-block (R14's cross-block overlap vanished when a partner block exited).
// Weight fusion inlined at startup; LDS arena phase-aliased.
__global__ __launch_bounds__(256) void gru_fused(
    const int* __restrict__ actor_ids, const int* __restrict__ action_ids,
    const int* __restrict__ street_ids, const float* __restrict__ bet,
    const int* __restrict__ mask,
    const float* __restrict__ E_actor, const float* __restrict__ E_action,
    const float* __restrict__ E_street, const float* __restrict__ W_proj,
    const float* __restrict__ b_proj, const float* __restrict__ W_ih,
    const float* __restrict__ b_ih, const float* __restrict__ W_hh,
    const float* __restrict__ b_hh, float* __restrict__ out)
{
    __shared__ __align__(16) union {
        float wfs[192][32];                            // startup: fused W_f
        struct {
            int pb[2][TT][17];                         // per-set ids|bet16
            __align__(16) _Float16 hb[2][2][16][72];   // [set][buf][n][72]
            int part[32][8];                           // mask popcount partials
            int Lsh[32];
        } c;
    } A;
    __shared__ __align__(16) _Float16 embl[144];
    __shared__ float bfs[192];                         // raw fused bias b_f

    const int tid = threadIdx.x;
    const int wv  = tid >> 6;        // wave = hid quarter
    const int l   = tid & 63;
    const int q   = l >> 4;          // quad
    const int n   = l & 15;          // batch col within group
    const int g   = blockIdx.x;      // rows [g*32, g*32+32)

    // embedding rows: 0..6 actor, 7..10 action, 11..15 street(+pad), 16 zero
    for (int i = tid; i < 136; i += 256) {
        int r = i >> 3, m = i & 7;
        float v = 0.f;
        if (r < 7)       v = E_actor[r * 8 + m];
        else if (r < 11) v = E_action[(r - 7) * 8 + m];
        else if (r < 16) v = (m < 4) ? E_street[(r - 11) * 4 + m] : 0.f;
        embl[i] = (_Float16)v;
    }

    // ---- startup: fused input weights (W_f = W_ih*W_proj, scaled) ----
    if (tid < 192) {
        const int j = tid;
        float wf[21];
        #pragma unroll
        for (int m = 0; m < 21; m++) wf[m] = 0.f;
        float bf = b_ih[j];
        for (int k = 0; k < 32; k++) {
            const float w = W_ih[j * 32 + k];
            bf += w * b_proj[k];
            #pragma unroll
            for (int m = 0; m < 21; m++) wf[m] += w * W_proj[k * 21 + m];
        }
        const float s = (j < 128) ? LOG2E : 2.f * LOG2E;   // exp2-fold
        #pragma unroll
        for (int m = 0; m < 21; m++) A.wfs[j][m] = wf[m] * s;
        #pragma unroll
        for (int m = 21; m < 32; m++) A.wfs[j][m] = 0.f;
        bfs[j] = bf;
    }
    __syncthreads();

    // ---- per-lane A-fragments + biases (A-layout A[m=l&15][k=(l>>4)*8+p]) ----
    half8 Af[3], Ah[3][2];
    {
        const int m16 = l & 15, kq = l >> 4;
        #pragma unroll
        for (int g3 = 0; g3 < 3; g3++) {
            const int jr = g3 * 64 + wv * 16 + m16;
            _Float16 v[8];
            #pragma unroll
            for (int m = 0; m < 8; m++) v[m] = (_Float16)A.wfs[jr][kq * 8 + m];
            Af[g3] = *(half8*)v;
            const float s = (g3 < 2) ? LOG2E : 2.f * LOG2E;
            #pragma unroll
            for (int kt = 0; kt < 2; kt++) {
                _Float16 w[8];
                #pragma unroll
                for (int m = 0; m < 8; m++)
                    w[m] = (_Float16)(W_hh[jr * HID + kt * 32 + kq * 8 + m] * s);
                Ah[g3][kt] = *(half8*)w;
            }
        }
    }
    f32x4 biasR, biasZ, biasX, biasH;
    #pragma unroll
    for (int e = 0; e < 4; e++) {
        const int idx = 16 * wv + 4 * q + e;
        biasR[e] = (bfs[idx]      + b_hh[idx])      * LOG2E;
        biasZ[e] = (bfs[64 + idx] + b_hh[64 + idx]) * LOG2E;
        biasX[e] = bfs[128 + idx]  * (2.f * LOG2E);
        biasH[e] = b_hh[128 + idx] * (2.f * LOG2E);
    }
    __syncthreads();   // wfs dead; arena becomes pb/hb/part

    // ---- stage both sets' pb + mask partials, zero hb ----
    for (int i = tid; i < (int)(sizeof(A.c.hb) / 4); i += 256) ((int*)A.c.hb)[i] = 0;
    {
        const int r = tid >> 3, tl = tid & 7;     // 32 rows x 8 threads
        const int s = r >> 4, rr = r & 15;
        const int base = (g * 32 + r) * TT;
        int cnt = 0;
        #pragma unroll
        for (int i = 0; i < 16; i++) {
            const int t = tl + 8 * i;
            const int a = actor_ids[base + t], c = action_ids[base + t];
            const int st = street_ids[base + t];
            const _Float16 f16 = (_Float16)bet[base + t];
            const unsigned fb = (unsigned)*(const unsigned short*)&f16;
            A.c.pb[s][t][rr] = (int)(a | (c << 3) | (st << 5) | (fb << 16));
            cnt += (mask[base + t] != 0);
        }
        A.c.part[r][tl] = cnt;
    }
    __syncthreads();
    if (tid < 32) {
        int L = 0;
        #pragma unroll
        for (int i = 0; i < 8; i++) L += A.c.part[tid][i];
        A.c.Lsh[tid] = L;
    }
    __syncthreads();

    const int Ln0 = A.c.Lsh[n];
    const int Ln1 = A.c.Lsh[16 + n];
    int Lmax = (Ln0 > Ln1) ? Ln0 : Ln1;   // butterfly max over 16 cols
    #pragma unroll
    for (int k = 1; k < 16; k <<= 1) {
        const int o = __shfl_xor(Lmax, k);
        Lmax = (o > Lmax) ? o : Lmax;
    }

    const bool isq2 = (q == 2);
    const int sh = (q == 1) ? 3 : (q == 2) ? 5 : 0;
    const int mk = (q == 1) ? 3 : (q == 3) ? 0 : 7;
    const int of = (q == 1) ? 7 : (q == 2) ? 11 : (q == 3) ? 16 : 0;

    float h0[4] = {0.f, 0.f, 0.f, 0.f};
    float h1[4] = {0.f, 0.f, 0.f, 0.f};

    // prime step-0 x-side accumulators for both sets
    f32x4 xR0, xZ0, xX0, xR1, xZ1, xX1;
    #pragma unroll
    for (int s = 0; s < 2; s++) {
        const int p = A.c.pb[s][0][n];
        const int eidx = ((p >> sh) & mk) + of;
        half8 Bf = *(const half8*)&embl[eidx * 8];
        uint4* bu = (uint4*)&Bf;
        bu->z = isq2 ? ((unsigned)p >> 16) : bu->z;   // {bet16,0} at k=20,21
        f32x4 r_ = __builtin_amdgcn_mfma_f32_16x16x32_f16(Af[0], Bf, biasR, 0, 0, 0);
        f32x4 z_ = __builtin_amdgcn_mfma_f32_16x16x32_f16(Af[1], Bf, biasZ, 0, 0, 0);
        f32x4 x_ = __builtin_amdgcn_mfma_f32_16x16x32_f16(Af[2], Bf, biasX, 0, 0, 0);
        if (s == 0) { xR0 = r_; xZ0 = z_; xX0 = x_; }
        else        { xR1 = r_; xZ1 = z_; xX1 = x_; }
    }

    for (int t = 0; t < Lmax; t++) {
        const int buf = t & 1;
        // h-side for both sets: independent depth-2 chains overlap
        const half8 B00 = *(const half8*)&A.c.hb[0][buf][n][q * 8];
        const half8 B01 = *(const half8*)&A.c.hb[0][buf][n][32 + q * 8];
        const half8 B10 = *(const half8*)&A.c.hb[1][buf][n][q * 8];
        const half8 B11 = *(const half8*)&A.c.hb[1][buf][n][32 + q * 8];

        f32x4 aR0 = __builtin_amdgcn_mfma_f32_16x16x32_f16(Ah[0][0], B00, xR0, 0, 0, 0);
        f32x4 aR1 = __builtin_amdgcn_mfma_f32_16x16x32_f16(Ah[0][0], B10, xR1, 0, 0, 0);
        f32x4 aZ0 = __builtin_amdgcn_mfma_f32_16x16x32_f16(Ah[1][0], B00, xZ0, 0, 0, 0);
        f32x4 aZ1 = __builtin_amdgcn_mfma_f32_16x16x32_f16(Ah[1][0], B10, xZ1, 0, 0, 0);
        f32x4 aH0 = __builtin_amdgcn_mfma_f32_16x16x32_f16(Ah[2][0], B00, biasH, 0, 0, 0);
        f32x4 aH1 = __builtin_amdgcn_mfma_f32_16x16x32_f16(Ah[2][0], B10, biasH, 0, 0, 0);
        aR0 = __builtin_amdgcn_mfma_f32_16x16x32_f16(Ah[0][1], B01, aR0, 0, 0, 0);
        aR1 = __builtin_amdgcn_mfma_f32_16x16x32_f16(Ah[0][1], B11, aR1, 0, 0, 0);
        aZ0 = __builtin_amdgcn_mfma_f32_16x16x32_f16(Ah[1][1], B01, aZ0, 0, 0, 0);
        aZ1 = __builtin_amdgcn_mfma_f32_16x16x32_f16(Ah[1][1], B11, aZ1, 0, 0, 0);
        aH0 = __builtin_amdgcn_mfma_f32_16x16x32_f16(Ah[2][1], B01, aH0, 0, 0, 0);
        aH1 = __builtin_amdgcn_mfma_f32_16x16x32_f16(Ah[2][1], B11, aH1, 0, 0, 0);
        const f32x4 aX0 = xX0, aX1 = xX1;

        // prefetch step t+1 x-side for both sets
        const int tn = (t + 1 < TT) ? t + 1 : TT - 1;
        {
            const int p = A.c.pb[0][tn][n];
            const int eidx = ((p >> sh) & mk) + of;
            half8 Bf = *(const half8*)&embl[eidx * 8];
            uint4* bu = (uint4*)&Bf;
            bu->z = isq2 ? ((unsigned)p >> 16) : bu->z;
            xR0 = __builtin_amdgcn_mfma_f32_16x16x32_f16(Af[0], Bf, biasR, 0, 0, 0);
            xZ0 = __builtin_amdgcn_mfma_f32_16x16x32_f16(Af[1], Bf, biasZ, 0, 0, 0);
            xX0 = __builtin_amdgcn_mfma_f32_16x16x32_f16(Af[2], Bf, biasX, 0, 0, 0);
        }
        {
            const int p = A.c.pb[1][tn][n];
            const int eidx = ((p >> sh) & mk) + of;
            half8 Bf = *(const half8*)&embl[eidx * 8];
            uint4* bu = (uint4*)&Bf;
            bu->z = isq2 ? ((unsigned)p >> 16) : bu->z;
            xR1 = __builtin_amdgcn_mfma_f32_16x16x32_f16(Af[0], Bf, biasR, 0, 0, 0);
            xZ1 = __builtin_amdgcn_mfma_f32_16x16x32_f16(Af[1], Bf, biasZ, 0, 0, 0);
            xX1 = __builtin_amdgcn_mfma_f32_16x16x32_f16(Af[2], Bf, biasX, 0, 0, 0);
        }

        // activations (exp2 domain), both sets
        const bool lv0 = (t < Ln0), lv1 = (t < Ln1);
        _Float16 hp0[4], hp1[4];
        #pragma unroll
        for (int e = 0; e < 4; e++) {
            {
                const float r = __builtin_amdgcn_rcpf(1.f + __builtin_amdgcn_exp2f(-aR0[e]));
                const float z = __builtin_amdgcn_rcpf(1.f + __builtin_amdgcn_exp2f(-aZ0[e]));
                const float y2 = aX0[e] + r * aH0[e];
                const float nn = 1.f - 2.f * __builtin_amdgcn_rcpf(1.f + __builtin_amdgcn_exp2f(y2));
                const float hv = nn + z * (h0[e] - nn);
                h0[e] = lv0 ? hv : h0[e];
                hp0[e] = (_Float16)h0[e];
            }
            {
                const float r = __builtin_amdgcn_rcpf(1.f + __builtin_amdgcn_exp2f(-aR1[e]));
                const float z = __builtin_amdgcn_rcpf(1.f + __builtin_amdgcn_exp2f(-aZ1[e]));
                const float y2 = aX1[e] + r * aH1[e];
                const float nn = 1.f - 2.f * __builtin_amdgcn_rcpf(1.f + __builtin_amdgcn_exp2f(y2));
                const float hv = nn + z * (h1[e] - nn);
                h1[e] = lv1 ? hv : h1[e];
                hp1[e] = (_Float16)h1[e];
            }
        }
        *(uint2*)&A.c.hb[0][buf ^ 1][n][16 * wv + 4 * q] = *(uint2*)hp0;
        *(uint2*)&A.c.hb[1][buf ^ 1][n][16 * wv + 4 * q] = *(uint2*)hp1;
        __syncthreads();
    }

    {
        float4 o = make_float4(h0[0], h0[1], h0[2], h0[3]);
        *(float4*)&out[(g * 32 + n) * HID + 16 * wv + 4 * q] = o;
    }
    {
        float4 o = make_float4(h1[0], h1[1], h1[2], h1[3]);
        *(float4*)&out[(g * 32 + 16 + n) * HID + 16 * wv + 4 * q] = o;
    }
}

extern "C" void kernel_launch(void* const* d_in, const int* in_sizes, int n_in,
                              void* d_out, int out_size, void* d_ws, size_t ws_size,
                              hipStream_t stream) {
    const int*   actor_ids  = (const int*)d_in[0];
    const int*   action_ids = (const int*)d_in[1];
    const int*   street_ids = (const int*)d_in[2];
    const float* bet        = (const float*)d_in[3];
    const int*   vmask      = (const int*)d_in[4];
    const float* E_actor    = (const float*)d_in[5];
    const float* E_action   = (const float*)d_in[6];
    const float* E_street   = (const float*)d_in[7];
    const float* W_proj     = (const float*)d_in[8];
    const float* b_proj     = (const float*)d_in[9];
    const float* W_ih       = (const float*)d_in[10];
    const float* W_hh       = (const float*)d_in[11];
    const float* b_ih       = (const float*)d_in[12];
    const float* b_hh       = (const float*)d_in[13];
    float*       out        = (float*)d_out;

    gru_fused<<<NBLK, 256, 0, stream>>>(actor_ids, action_ids, street_ids, bet,
                                        vmask, E_actor, E_action, E_street,
                                        W_proj, b_proj, W_ih, b_ih, W_hh, b_hh,
                                        out);
}

// Round 16
// 189.113 us; speedup vs baseline: 1.0343x; 1.0343x over previous
//
#include <hip/hip_runtime.h>

#define HID 64
#define TT  128
#define NROWS 8192
#define NGRP (NROWS / 16)   // 512 groups of 16 length-sorted rows
#define LOG2E 1.44269504088896f

typedef _Float16 half8 __attribute__((ext_vector_type(8)));
typedef float    f32x4 __attribute__((ext_vector_type(4)));

// d_ws byte layout
#define WS_WF    0        // 12 tiles * 64 lanes * 8 f16
#define WS_WHH   12288    // 12 * 2kt * 64 * 8 f16
#define WS_BA    36864    // 128 f32 fused bias r,z (log2e-scaled)
#define WS_BX    37376    // 64 f32 b_f n-side (2log2e-scaled)
#define WS_BH    37632    // 64 f32 b_hh n-side (2log2e-scaled)
#define WS_EMB   37888    // 17*8 f16 embedding rows
#define WS_LROW  38176    // 8192 i32 per-row length

// blocks 0..63: per-row lengths via partial sums (8 iters of 16 rows x 16 thr,
// coalesced). block 64: weight fusion + MFMA A-tile emission + emb table.
__global__ __launch_bounds__(256) void prep(
    const float* __restrict__ E_actor, const float* __restrict__ E_action,
    const float* __restrict__ E_street, const float* __restrict__ W_proj,
    const float* __restrict__ b_proj, const float* __restrict__ W_ih,
    const float* __restrict__ b_ih, const float* __restrict__ W_hh,
    const float* __restrict__ b_hh, const int* __restrict__ mask,
    char* __restrict__ ws)
{
    const int j = threadIdx.x;
    if (blockIdx.x != 64) {
        int* Lrow = (int*)(ws + WS_LROW);
        __shared__ int part[16][16];
        const int r = j >> 4, tl = j & 15;
        for (int it = 0; it < 8; it++) {
            const int row = blockIdx.x * 128 + it * 16 + r;
            const int base = row * TT;
            int cnt = 0;
            #pragma unroll
            for (int i = 0; i < 8; i++) cnt += (mask[base + tl + 16 * i] != 0);
            part[r][tl] = cnt;
            __syncthreads();
            if (j < 16) {
                int L = 0;
                #pragma unroll
                for (int i = 0; i < 16; i++) L += part[j][i];
                Lrow[blockIdx.x * 128 + it * 16 + j] = L;
            }
            __syncthreads();
        }
        return;
    }

    _Float16* WF  = (_Float16*)(ws + WS_WF);
    _Float16* WHH = (_Float16*)(ws + WS_WHH);
    float*    BA  = (float*)(ws + WS_BA);
    float*    BX  = (float*)(ws + WS_BX);
    float*    BH  = (float*)(ws + WS_BH);
    _Float16* EMB = (_Float16*)(ws + WS_EMB);

    __shared__ float wfs[192][32];
    if (j < 192) {
        // W_f[j][m] = sum_k W_ih[j,k]*W_proj[k,m]; b_f = b_ih + W_ih*b_proj
        float wf[21];
        #pragma unroll
        for (int m = 0; m < 21; m++) wf[m] = 0.f;
        float bf = b_ih[j];
        for (int k = 0; k < 32; k++) {
            float w = W_ih[j * 32 + k];
            bf += w * b_proj[k];
            #pragma unroll
            for (int m = 0; m < 21; m++) wf[m] += w * W_proj[k * 21 + m];
        }
        // fold log2e (r,z rows) / 2log2e (n rows): activations become raw exp2
        const float s = (j < 128) ? LOG2E : 2.f * LOG2E;
        #pragma unroll
        for (int m = 0; m < 21; m++) wfs[j][m] = wf[m] * s;
        #pragma unroll
        for (int m = 21; m < 32; m++) wfs[j][m] = 0.f;
        if (j < 128) BA[j] = (bf + b_hh[j]) * LOG2E;
        else { BX[j - 128] = bf * 2.f * LOG2E; BH[j - 128] = b_hh[j] * 2.f * LOG2E; }
    }
    if (j < 17 * 8) {   // emb rows: 0..6 actor, 7..10 action, 11..15 street, 16 zero
        int r = j >> 3, m = j & 7;
        float v = 0.f;
        if (r < 7)       v = E_actor[r * 8 + m];
        else if (r < 11) v = E_action[(r - 7) * 8 + m];
        else if (r < 16) v = (m < 4) ? E_street[(r - 11) * 4 + m] : 0.f;
        EMB[j] = (_Float16)v;
    }
    __syncthreads();

    // A-layout: A[m=lane&15][k=(lane>>4)*8+pos]
    for (int idx = j; idx < 12 * 64; idx += 256) {
        const int T = idx >> 6, lane = idx & 63;
        const int g3 = T >> 2, w = T & 3, m16 = lane & 15, kq = lane >> 4;
        const int jr = g3 * 64 + w * 16 + m16;
        _Float16 v[8];
        #pragma unroll
        for (int m = 0; m < 8; m++) v[m] = (_Float16)wfs[jr][kq * 8 + m];
        *(uint4*)&WF[idx * 8] = *(uint4*)v;
    }
    for (int idx = j; idx < 12 * 2 * 64; idx += 256) {
        const int T = idx >> 7, rem = idx & 127, kt = rem >> 6, lane = rem & 63;
        const int g3 = T >> 2, w = T & 3, m16 = lane & 15, kq = lane >> 4;
        const int jr = g3 * 64 + w * 16 + m16;
        const int kbase = kt * 32 + kq * 8;
        const float s = (jr < 128) ? LOG2E : 2.f * LOG2E;
        _Float16 v[8];
        #pragma unroll
        for (int m = 0; m < 8; m++) v[m] = (_Float16)(W_hh[jr * HID + kbase + m] * s);
        *(uint4*)&WHH[((T * 2 + kt) * 64 + lane) * 8] = *(uint4*)v;
    }
}

// One 256-thread block (4 waves) per 16-row group. Startup: in-block sort —
// LDS histogram of all 8192 lengths, prefix scan, filter candidate rows whose
// bins intersect this block's 16-slot window, bitonic-sort (L,idx) keys, pick
// 16. Loop: R11's measured-best (67.5us) step structure, unchanged.
__global__ __launch_bounds__(256, 2) void gru_mfma(
    const int* __restrict__ actor_ids, const int* __restrict__ action_ids,
    const int* __restrict__ street_ids, const float* __restrict__ bet,
    const char* __restrict__ ws, const int* __restrict__ Lrow,
    float* __restrict__ out)
{
    const _Float16* WF  = (const _Float16*)(ws + WS_WF);
    const _Float16* WHH = (const _Float16*)(ws + WS_WHH);
    const float*    BA  = (const float*)(ws + WS_BA);
    const float*    BX  = (const float*)(ws + WS_BX);
    const float*    BH  = (const float*)(ws + WS_BH);
    const _Float16* EMB = (const _Float16*)(ws + WS_EMB);

    __shared__ __align__(16) union {
        struct {                                      // startup: sort scratch
            int hist[129];
            int pref[129];
            int cand[512];                            // key = (L<<13)|rowidx
            int ncand;
        } s;
        struct {                                      // main loop arena
            int pb[TT][17];                           // ids|bet16, padded
            __align__(16) _Float16 hb[2][16][72];     // h f16 dbuf, stride 72
        } c;
    } A;
    __shared__ __align__(16) _Float16 embl[144];
    __shared__ int ordr[16];                          // this block's 16 rows
    __shared__ int Lw[16];                            // their lengths (ascending)

    const int tid = threadIdx.x;
    const int wv  = tid >> 6;        // wave = hid quarter
    const int l   = tid & 63;
    const int q   = l >> 4;          // quad
    const int n   = l & 15;          // batch col within group

    const int b = blockIdx.x;
    const int g = (b & 1) ? (NGRP - 1 - (b >> 1)) : (b >> 1);   // long/short pairing
    const int s0 = g * 16;           // sorted-slot window [s0, s0+16)

    for (int i = tid; i < 136; i += 256) embl[i] = EMB[i];

    // ---- in-block sort: histogram -> prefix -> filter -> bitonic -> pick ----
    for (int i = tid; i < 129; i += 256) A.s.hist[i] = 0;
    if (tid == 0) A.s.ncand = 0;
    __syncthreads();
    for (int i = tid; i < NROWS; i += 256) atomicAdd(&A.s.hist[Lrow[i]], 1);
    __syncthreads();
    if (tid == 0) {
        int run = 0;
        for (int i = 0; i < 129; i++) { A.s.pref[i] = run; run += A.s.hist[i]; }
    }
    __syncthreads();
    for (int i = tid; i < NROWS; i += 256) {
        const int L = Lrow[i];
        if (A.s.pref[L] < s0 + 16 && A.s.pref[L] + A.s.hist[L] > s0) {
            const int k = atomicAdd(&A.s.ncand, 1);
            if (k < 512) A.s.cand[k] = (L << 13) | i;
        }
    }
    __syncthreads();
    const int nc = A.s.ncand;
    for (int i = tid; i < 512; i += 256) if (i >= nc) A.s.cand[i] = 0x7fffffff;
    // bitonic sort 512 ascending (keys (L,idx) -> counting-sort order)
    for (int k = 2; k <= 512; k <<= 1) {
        for (int jj = k >> 1; jj > 0; jj >>= 1) {
            __syncthreads();
            for (int w = tid; w < 512; w += 256) {
                const int ixj = w ^ jj;
                if (ixj > w) {
                    const int a = A.s.cand[w], bb = A.s.cand[ixj];
                    const bool up = ((w & k) == 0);
                    if ((a > bb) == up) { A.s.cand[w] = bb; A.s.cand[ixj] = a; }
                }
            }
        }
    }
    __syncthreads();
    if (tid < 16) {
        const int off = s0 - A.s.pref[A.s.cand[0] >> 13];   // cand[0] = global pos pref[Lmin]
        const int key = A.s.cand[off + tid];
        ordr[tid] = key & 8191;
        Lw[tid]   = key >> 13;
    }
    __syncthreads();   // sort scratch dead; arena becomes pb/hb

    // ---- stage packed ids+bet16, zero hb ----
    for (int i = tid; i < 2 * 16 * 72 / 2; i += 256) ((int*)A.c.hb)[i] = 0;
    {
        const int r = tid >> 4, tl = tid & 15;
        const int base = ordr[r] * TT;
        #pragma unroll
        for (int i = 0; i < 8; i++) {
            const int t = tl + 16 * i;
            const int a = actor_ids[base + t], c = action_ids[base + t];
            const int s = street_ids[base + t];
            const _Float16 f16 = (_Float16)bet[base + t];
            const unsigned fb = (unsigned)*(const unsigned short*)&f16;
            A.c.pb[t][r] = (int)(a | (c << 3) | (s << 5) | (fb << 16));
        }
    }

    // loop-invariant A-fragments (AGPR-resident is fine for MFMA operands)
    half8 Af[3], Ah[3][2];
    #pragma unroll
    for (int g3 = 0; g3 < 3; g3++) {
        const int T = g3 * 4 + wv;
        Af[g3]    = *(const half8*)&WF[(T * 64 + l) * 8];
        Ah[g3][0] = *(const half8*)&WHH[((T * 2 + 0) * 64 + l) * 8];
        Ah[g3][1] = *(const half8*)&WHH[((T * 2 + 1) * 64 + l) * 8];
    }
    f32x4 biasR, biasZ, biasX, biasH;
    #pragma unroll
    for (int e = 0; e < 4; e++) {
        const int idx = 16 * wv + 4 * q + e;
        biasR[e] = BA[idx];
        biasZ[e] = BA[64 + idx];
        biasX[e] = BX[idx];
        biasH[e] = BH[idx];
    }

    const int myrow = ordr[n];
    const int Ln    = Lw[n];
    const int Lmax  = Lw[15];        // ascending -> slot 15 holds block max
    const bool isq2 = (q == 2);
    const int sh = (q == 1) ? 3 : (q == 2) ? 5 : 0;
    const int mk = (q == 1) ? 3 : (q == 3) ? 0 : 7;
    const int of = (q == 1) ? 7 : (q == 2) ? 11 : (q == 3) ? 16 : 0;

    float h[4] = {0.f, 0.f, 0.f, 0.f};
    __syncthreads();   // pb/hb visible

    // prime step-0 x-side accumulators
    f32x4 xR, xZ, xX;
    {
        const int p = A.c.pb[0][n];
        const int eidx = ((p >> sh) & mk) + of;
        half8 Bf = *(const half8*)&embl[eidx * 8];
        uint4* bu = (uint4*)&Bf;
        bu->z = isq2 ? ((unsigned)p >> 16) : bu->z;   // {bet16, 0} at k=20,21
        xR = __builtin_amdgcn_mfma_f32_16x16x32_f16(Af[0], Bf, biasR, 0, 0, 0);
        xZ = __builtin_amdgcn_mfma_f32_16x16x32_f16(Af[1], Bf, biasZ, 0, 0, 0);
        xX = __builtin_amdgcn_mfma_f32_16x16x32_f16(Af[2], Bf, biasX, 0, 0, 0);
    }

    for (int t = 0; t < Lmax; t++) {
        const int buf = t & 1;
        const half8 Bh0 = *(const half8*)&A.c.hb[buf][n][q * 8];
        const half8 Bh1 = *(const half8*)&A.c.hb[buf][n][32 + q * 8];
        // K-tiles chained through the C operand (3 independent depth-2 chains)
        f32x4 aR = __builtin_amdgcn_mfma_f32_16x16x32_f16(Ah[0][0], Bh0, xR, 0, 0, 0);
        aR = __builtin_amdgcn_mfma_f32_16x16x32_f16(Ah[0][1], Bh1, aR, 0, 0, 0);
        f32x4 aZ = __builtin_amdgcn_mfma_f32_16x16x32_f16(Ah[1][0], Bh0, xZ, 0, 0, 0);
        aZ = __builtin_amdgcn_mfma_f32_16x16x32_f16(Ah[1][1], Bh1, aZ, 0, 0, 0);
        f32x4 aH = __builtin_amdgcn_mfma_f32_16x16x32_f16(Ah[2][0], Bh0, biasH, 0, 0, 0);
        aH = __builtin_amdgcn_mfma_f32_16x16x32_f16(Ah[2][1], Bh1, aH, 0, 0, 0);
        const f32x4 aXc = xX;

        // prefetch step t+1 x-side (independent of this step's h)
        {
            const int tn = (t + 1 < TT) ? t + 1 : TT - 1;
            const int p = A.c.pb[tn][n];
            const int eidx = ((p >> sh) & mk) + of;
            half8 Bf = *(const half8*)&embl[eidx * 8];
            uint4* bu = (uint4*)&Bf;
            bu->z = isq2 ? ((unsigned)p >> 16) : bu->z;
            xR = __builtin_amdgcn_mfma_f32_16x16x32_f16(Af[0], Bf, biasR, 0, 0, 0);
            xZ = __builtin_amdgcn_mfma_f32_16x16x32_f16(Af[1], Bf, biasZ, 0, 0, 0);
            xX = __builtin_amdgcn_mfma_f32_16x16x32_f16(Af[2], Bf, biasX, 0, 0, 0);
        }

        const bool live = (t < Ln);
        _Float16 hp[4];
        #pragma unroll
        for (int e = 0; e < 4; e++) {
            // weights pre-scaled: aR,aZ in log2 domain; aX,aH in 2log2e domain
            const float r = __builtin_amdgcn_rcpf(1.f + __builtin_amdgcn_exp2f(-aR[e]));
            const float z = __builtin_amdgcn_rcpf(1.f + __builtin_amdgcn_exp2f(-aZ[e]));
            const float y2 = aXc[e] + r * aH[e];           // = 2*log2e*y
            const float nn = 1.f - 2.f * __builtin_amdgcn_rcpf(1.f + __builtin_amdgcn_exp2f(y2));
            const float hv = nn + z * (h[e] - nn);
            h[e] = live ? hv : h[e];
            hp[e] = (_Float16)h[e];
        }
        *(uint2*)&A.c.hb[buf ^ 1][n][16 * wv + 4 * q] = *(uint2*)hp;
        __syncthreads();
    }

    float4 o = make_float4(h[0], h[1], h[2], h[3]);
    *(float4*)&out[myrow * HID + 16 * wv + 4 * q] = o;
}

extern "C" void kernel_launch(void* const* d_in, const int* in_sizes, int n_in,
                              void* d_out, int out_size, void* d_ws, size_t ws_size,
                              hipStream_t stream) {
    const int*   actor_ids  = (const int*)d_in[0];
    const int*   action_ids = (const int*)d_in[1];
    const int*   street_ids = (const int*)d_in[2];
    const float* bet        = (const float*)d_in[3];
    const int*   vmask      = (const int*)d_in[4];
    const float* E_actor    = (const float*)d_in[5];
    const float* E_action   = (const float*)d_in[6];
    const float* E_street   = (const float*)d_in[7];
    const float* W_proj     = (const float*)d_in[8];
    const float* b_proj     = (const float*)d_in[9];
    const float* W_ih       = (const float*)d_in[10];
    const float* W_hh       = (const float*)d_in[11];
    const float* b_ih       = (const float*)d_in[12];
    const float* b_hh       = (const float*)d_in[13];
    float*       out        = (float*)d_out;

    char* ws = (char*)d_ws;
    int*  Lrow = (int*)(ws + WS_LROW);

    prep<<<65, 256, 0, stream>>>(E_actor, E_action, E_street, W_proj, b_proj,
                                 W_ih, b_ih, W_hh, b_hh, vmask, ws);
    gru_mfma<<<NGRP, 256, 0, stream>>>(actor_ids, action_ids, street_ids, bet,
                                       ws, Lrow, out);
}

// Round 17
// 172.553 us; speedup vs baseline: 1.1336x; 1.0960x over previous
//
#include <hip/hip_runtime.h>

#define HID 64
#define TT  128
#define NROWS 8192
#define NGRP (NROWS / 16)   // 512 groups of 16 length-sorted rows
#define LOG2E 1.44269504088896f

typedef _Float16 half8 __attribute__((ext_vector_type(8)));
typedef float    f32x4 __attribute__((ext_vector_type(4)));

// dispatch 1: per-row valid lengths -> d_ws (64 blocks, coalesced mask reads)
__global__ __launch_bounds__(256) void lens(const int* __restrict__ mask,
                                            int* __restrict__ Lrow)
{
    __shared__ int part[16][16];
    const int j = threadIdx.x;
    const int r = j >> 4, tl = j & 15;
    for (int it = 0; it < 8; it++) {
        const int row = blockIdx.x * 128 + it * 16 + r;
        const int base = row * TT;
        int cnt = 0;
        #pragma unroll
        for (int i = 0; i < 8; i++) cnt += (mask[base + tl + 16 * i] != 0);
        part[r][tl] = cnt;
        __syncthreads();
        if (j < 16) {
            int L = 0;
            #pragma unroll
            for (int i = 0; i < 16; i++) L += part[j][i];
            Lrow[blockIdx.x * 128 + it * 16 + j] = L;
        }
        __syncthreads();
    }
}

// dispatch 2: single fused GRU. Startup phases (LDS arena aliased 3 ways):
//  S: lean sorted-window selection — lengths into 32 regs/thread, LDS
//     histogram, parallel 129-prefix, candidate filter from regs, rank by
//     counting over the small candidate list (no bitonic, no serial scan).
//  W: inline weight fusion (R14-measured ~5us).
//  C: R11's measured-best step loop (67.5us sorted).
__global__ __launch_bounds__(256, 2) void gru_fused(
    const int* __restrict__ actor_ids, const int* __restrict__ action_ids,
    const int* __restrict__ street_ids, const float* __restrict__ bet,
    const float* __restrict__ E_actor, const float* __restrict__ E_action,
    const float* __restrict__ E_street, const float* __restrict__ W_proj,
    const float* __restrict__ b_proj, const float* __restrict__ W_ih,
    const float* __restrict__ b_ih, const float* __restrict__ W_hh,
    const float* __restrict__ b_hh, const int* __restrict__ Lrow,
    float* __restrict__ out)
{
    __shared__ __align__(16) union {
        struct {                                      // S: selection scratch
            int hist[129];
            int pref[129];
            int cand[512];                            // key = (L<<13)|rowidx
            int ncand;
        } s;
        float wfs[192][32];                           // W: fused W_f (scaled)
        struct {                                      // C: main loop arena
            int pb[TT][17];                           // ids|bet16, padded
            __align__(16) _Float16 hb[2][16][72];     // h f16 dbuf, stride 72
        } c;
    } A;
    __shared__ __align__(16) _Float16 embl[144];
    __shared__ float bfs[192];                        // raw fused bias b_f
    __shared__ int ordr[16], Lw[16];                  // block's rows + lengths

    const int tid = threadIdx.x;
    const int wv  = tid >> 6;        // wave = hid quarter
    const int l   = tid & 63;
    const int q   = l >> 4;          // quad
    const int n   = l & 15;          // batch col within group

    const int b  = blockIdx.x;
    const int g  = (b & 1) ? (NGRP - 1 - (b >> 1)) : (b >> 1);  // long/short pair
    const int w0 = g * 16;           // sorted-slot window [w0, w0+16)

    // embedding rows: 0..6 actor, 7..10 action, 11..15 street(+pad), 16 zero
    for (int i = tid; i < 136; i += 256) {
        int r = i >> 3, m = i & 7;
        float v = 0.f;
        if (r < 7)       v = E_actor[r * 8 + m];
        else if (r < 11) v = E_action[(r - 7) * 8 + m];
        else if (r < 16) v = (m < 4) ? E_street[(r - 11) * 4 + m] : 0.f;
        embl[i] = (_Float16)v;
    }

    // ---- Phase S: selection ----
    int Lreg[32];
    #pragma unroll
    for (int i = 0; i < 32; i++) Lreg[i] = Lrow[i * 256 + tid];   // L2-hot 8KB
    for (int i = tid; i < 129; i += 256) A.s.hist[i] = 0;
    if (tid == 0) A.s.ncand = 0;
    if (tid < 16) { ordr[tid] = 0; Lw[tid] = 0; }     // overflow-safe default
    __syncthreads();
    #pragma unroll
    for (int i = 0; i < 32; i++) atomicAdd(&A.s.hist[Lreg[i]], 1);
    __syncthreads();
    if (tid < 129) A.s.pref[tid] = A.s.hist[tid];     // inclusive scan
    __syncthreads();
    for (int d = 1; d < 129; d <<= 1) {
        int v = 0;
        if (tid < 129 && tid >= d) v = A.s.pref[tid - d];
        __syncthreads();
        if (tid < 129) A.s.pref[tid] += v;
        __syncthreads();
    }
    // candidate rows: bins intersecting the window (from registers, no rescan)
    #pragma unroll
    for (int i = 0; i < 32; i++) {
        const int L = Lreg[i];
        const int e = A.s.pref[L] - A.s.hist[L];      // exclusive bin start
        if (e < w0 + 16 && A.s.pref[L] > w0) {
            const int k = atomicAdd(&A.s.ncand, 1);
            if (k < 512) A.s.cand[k] = (L << 13) | (i * 256 + tid);
        }
    }
    __syncthreads();
    {   // rank each candidate: global pos = bin_start + in-bin idx-rank
        const int nc = (A.s.ncand < 512) ? A.s.ncand : 512;
        for (int i = tid; i < nc; i += 256) {
            const int key = A.s.cand[i];
            const int L = key >> 13, lo = L << 13;
            int r = A.s.pref[L] - A.s.hist[L];
            for (int jj = 0; jj < nc; jj++) {         // broadcast reads
                const int k2 = A.s.cand[jj];
                r += (k2 >= lo && k2 < key);
            }
            if (r >= w0 && r < w0 + 16) { ordr[r - w0] = key & 8191; Lw[r - w0] = L; }
        }
    }
    __syncthreads();   // selection scratch dead

    // ---- Phase W: inline weight fusion (W_f = W_ih*W_proj, exp2-scaled) ----
    if (tid < 192) {
        const int j = tid;
        float wf[21];
        #pragma unroll
        for (int m = 0; m < 21; m++) wf[m] = 0.f;
        float bf = b_ih[j];
        for (int k = 0; k < 32; k++) {
            const float w = W_ih[j * 32 + k];
            bf += w * b_proj[k];
            #pragma unroll
            for (int m = 0; m < 21; m++) wf[m] += w * W_proj[k * 21 + m];
        }
        const float s = (j < 128) ? LOG2E : 2.f * LOG2E;
        #pragma unroll
        for (int m = 0; m < 21; m++) A.wfs[j][m] = wf[m] * s;
        #pragma unroll
        for (int m = 21; m < 32; m++) A.wfs[j][m] = 0.f;
        bfs[j] = bf;
    }
    __syncthreads();

    // per-lane A-fragments (A-layout A[m=l&15][k=(l>>4)*8+p]) + biases
    half8 Af[3], Ah[3][2];
    {
        const int m16 = l & 15, kq = l >> 4;
        #pragma unroll
        for (int g3 = 0; g3 < 3; g3++) {
            const int jr = g3 * 64 + wv * 16 + m16;
            _Float16 v[8];
            #pragma unroll
            for (int m = 0; m < 8; m++) v[m] = (_Float16)A.wfs[jr][kq * 8 + m];
            Af[g3] = *(half8*)v;
            const float s = (g3 < 2) ? LOG2E : 2.f * LOG2E;
            #pragma unroll
            for (int kt = 0; kt < 2; kt++) {
                _Float16 w[8];
                #pragma unroll
                for (int m = 0; m < 8; m++)
                    w[m] = (_Float16)(W_hh[jr * HID + kt * 32 + kq * 8 + m] * s);
                Ah[g3][kt] = *(half8*)w;
            }
        }
    }
    f32x4 biasR, biasZ, biasX, biasH;
    #pragma unroll
    for (int e = 0; e < 4; e++) {
        const int idx = 16 * wv + 4 * q + e;
        biasR[e] = (bfs[idx]      + b_hh[idx])      * LOG2E;
        biasZ[e] = (bfs[64 + idx] + b_hh[64 + idx]) * LOG2E;
        biasX[e] = bfs[128 + idx]  * (2.f * LOG2E);
        biasH[e] = b_hh[128 + idx] * (2.f * LOG2E);
    }
    __syncthreads();   // wfs dead; arena becomes pb/hb

    // ---- Phase C: stage pb/hb, then R11's measured-best loop ----
    for (int i = tid; i < 2 * 16 * 72 / 2; i += 256) ((int*)A.c.hb)[i] = 0;
    {
        const int r = tid >> 4, tl = tid & 15;
        const int base = ordr[r] * TT;
        #pragma unroll
        for (int i = 0; i < 8; i++) {
            const int t = tl + 16 * i;
            const int a = actor_ids[base + t], c = action_ids[base + t];
            const int s = street_ids[base + t];
            const _Float16 f16 = (_Float16)bet[base + t];
            const unsigned fb = (unsigned)*(const unsigned short*)&f16;
            A.c.pb[t][r] = (int)(a | (c << 3) | (s << 5) | (fb << 16));
        }
    }

    const int myrow = ordr[n];
    const int Ln    = Lw[n];
    const int Lmax  = Lw[15];        // ascending window -> slot 15 is max
    const bool isq2 = (q == 2);
    const int sh = (q == 1) ? 3 : (q == 2) ? 5 : 0;
    const int mk = (q == 1) ? 3 : (q == 3) ? 0 : 7;
    const int of = (q == 1) ? 7 : (q == 2) ? 11 : (q == 3) ? 16 : 0;

    float h[4] = {0.f, 0.f, 0.f, 0.f};
    __syncthreads();   // pb/hb visible

    // prime step-0 x-side accumulators
    f32x4 xR, xZ, xX;
    {
        const int p = A.c.pb[0][n];
        const int eidx = ((p >> sh) & mk) + of;
        half8 Bf = *(const half8*)&embl[eidx * 8];
        uint4* bu = (uint4*)&Bf;
        bu->z = isq2 ? ((unsigned)p >> 16) : bu->z;   // {bet16, 0} at k=20,21
        xR = __builtin_amdgcn_mfma_f32_16x16x32_f16(Af[0], Bf, biasR, 0, 0, 0);
        xZ = __builtin_amdgcn_mfma_f32_16x16x32_f16(Af[1], Bf, biasZ, 0, 0, 0);
        xX = __builtin_amdgcn_mfma_f32_16x16x32_f16(Af[2], Bf, biasX, 0, 0, 0);
    }

    for (int t = 0; t < Lmax; t++) {
        const int buf = t & 1;
        const half8 Bh0 = *(const half8*)&A.c.hb[buf][n][q * 8];
        const half8 Bh1 = *(const half8*)&A.c.hb[buf][n][32 + q * 8];
        // K-tiles chained through the C operand (3 independent depth-2 chains)
        f32x4 aR = __builtin_amdgcn_mfma_f32_16x16x32_f16(Ah[0][0], Bh0, xR, 0, 0, 0);
        aR = __builtin_amdgcn_mfma_f32_16x16x32_f16(Ah[0][1], Bh1, aR, 0, 0, 0);
        f32x4 aZ = __builtin_amdgcn_mfma_f32_16x16x32_f16(Ah[1][0], Bh0, xZ, 0, 0, 0);
        aZ = __builtin_amdgcn_mfma_f32_16x16x32_f16(Ah[1][1], Bh1, aZ, 0, 0, 0);
        f32x4 aH = __builtin_amdgcn_mfma_f32_16x16x32_f16(Ah[2][0], Bh0, biasH, 0, 0, 0);
        aH = __builtin_amdgcn_mfma_f32_16x16x32_f16(Ah[2][1], Bh1, aH, 0, 0, 0);
        const f32x4 aXc = xX;

        // prefetch step t+1 x-side (independent of this step's h)
        {
            const int tn = (t + 1 < TT) ? t + 1 : TT - 1;
            const int p = A.c.pb[tn][n];
            const int eidx = ((p >> sh) & mk) + of;
            half8 Bf = *(const half8*)&embl[eidx * 8];
            uint4* bu = (uint4*)&Bf;
            bu->z = isq2 ? ((unsigned)p >> 16) : bu->z;
            xR = __builtin_amdgcn_mfma_f32_16x16x32_f16(Af[0], Bf, biasR, 0, 0, 0);
            xZ = __builtin_amdgcn_mfma_f32_16x16x32_f16(Af[1], Bf, biasZ, 0, 0, 0);
            xX = __builtin_amdgcn_mfma_f32_16x16x32_f16(Af[2], Bf, biasX, 0, 0, 0);
        }

        const bool live = (t < Ln);
        _Float16 hp[4];
        #pragma unroll
        for (int e = 0; e < 4; e++) {
            // weights pre-scaled: aR,aZ in log2 domain; aX,aH in 2log2e domain
            const float r = __builtin_amdgcn_rcpf(1.f + __builtin_amdgcn_exp2f(-aR[e]));
            const float z = __builtin_amdgcn_rcpf(1.f + __builtin_amdgcn_exp2f(-aZ[e]));
            const float y2 = aXc[e] + r * aH[e];           // = 2*log2e*y
            const float nn = 1.f - 2.f * __builtin_amdgcn_rcpf(1.f + __builtin_amdgcn_exp2f(y2));
            const float hv = nn + z * (h[e] - nn);
            h[e] = live ? hv : h[e];
            hp[e] = (_Float16)h[e];
        }
        *(uint2*)&A.c.hb[buf ^ 1][n][16 * wv + 4 * q] = *(uint2*)hp;
        __syncthreads();
    }

    float4 o = make_float4(h[0], h[1], h[2], h[3]);
    *(float4*)&out[myrow * HID + 16 * wv + 4 * q] = o;
}

extern "C" void kernel_launch(void* const* d_in, const int* in_sizes, int n_in,
                              void* d_out, int out_size, void* d_ws, size_t ws_size,
                              hipStream_t stream) {
    const int*   actor_ids  = (const int*)d_in[0];
    const int*   action_ids = (const int*)d_in[1];
    const int*   street_ids = (const int*)d_in[2];
    const float* bet        = (const float*)d_in[3];
    const int*   vmask      = (const int*)d_in[4];
    const float* E_actor    = (const float*)d_in[5];
    const float* E_action   = (const float*)d_in[6];
    const float* E_street   = (const float*)d_in[7];
    const float* W_proj     = (const float*)d_in[8];
    const float* b_proj     = (const float*)d_in[9];
    const float* W_ih       = (const float*)d_in[10];
    const float* W_hh       = (const float*)d_in[11];
    const float* b_ih       = (const float*)d_in[12];
    const float* b_hh       = (const float*)d_in[13];
    float*       out        = (float*)d_out;
    int*         Lrow       = (int*)d_ws;

    lens<<<64, 256, 0, stream>>>(vmask, Lrow);
    gru_fused<<<NGRP, 256, 0, stream>>>(actor_ids, action_ids, street_ids, bet,
                                        E_actor, E_action, E_street, W_proj,
                                        b_proj, W_ih, b_ih, W_hh, b_hh, Lrow,
                                        out);
}

// Round 18
// 166.670 us; speedup vs baseline: 1.1736x; 1.0353x over previous
//
#include <hip/hip_runtime.h>

#define HID 64
#define TT  128
#define NROWS 8192
#define NGRP (NROWS / 16)   // 512 blocks of 16 rows; exactly 2 blocks/CU
#define LOG2E 1.44269504088896f

typedef _Float16 half8 __attribute__((ext_vector_type(8)));
typedef float    f32x4 __attribute__((ext_vector_type(4)));

// Single-dispatch GRU (measured optimum, R14): per-block inline weight fusion
// (redundant but parallel and L2-hot), in-kernel row lengths, R11's
// measured-best step loop. LDS arena phase-aliased: wfs -> pb/hb/part.
// Session ledger: sorted-loop variants (R11/R13/R16/R17) run the loop at 67.5us
// but every sorting mechanism costs >= 25us machinery+dispatch -> all converge
// to >= 165us total. This single-dispatch unsorted kernel hits 165.2us with
// none of that. Binding constraints: ~70us fixed harness floor + chain-latency
// x max-L (some block always runs 128 steps at ~1100-1250 cyc/step solo).
__global__ __launch_bounds__(256, 2) void gru_fused(
    const int* __restrict__ actor_ids, const int* __restrict__ action_ids,
    const int* __restrict__ street_ids, const float* __restrict__ bet,
    const int* __restrict__ mask,
    const float* __restrict__ E_actor, const float* __restrict__ E_action,
    const float* __restrict__ E_street, const float* __restrict__ W_proj,
    const float* __restrict__ b_proj, const float* __restrict__ W_ih,
    const float* __restrict__ b_ih, const float* __restrict__ W_hh,
    const float* __restrict__ b_hh, float* __restrict__ out)
{
    __shared__ __align__(16) union {
        float wfs[192][32];                           // startup: fused W_f (scaled)
        struct {
            int pb[TT][17];                           // ids|bet16, padded
            __align__(16) _Float16 hb[2][16][72];     // h f16 dbuf, stride 72
            int part[16][16];                         // mask popcount partials
            int Lsh[16];
        } c;
    } A;
    __shared__ __align__(16) _Float16 embl[144];
    __shared__ float bfs[192];                        // raw fused bias b_f

    const int tid = threadIdx.x;
    const int wv  = tid >> 6;        // wave = hid quarter
    const int l   = tid & 63;
    const int q   = l >> 4;          // quad
    const int n   = l & 15;          // batch col within group
    const int g   = blockIdx.x;

    // embedding rows: 0..6 actor, 7..10 action, 11..15 street(+pad), 16 zero
    for (int i = tid; i < 136; i += 256) {
        int r = i >> 3, m = i & 7;
        float v = 0.f;
        if (r < 7)       v = E_actor[r * 8 + m];
        else if (r < 11) v = E_action[(r - 7) * 8 + m];
        else if (r < 16) v = (m < 4) ? E_street[(r - 11) * 4 + m] : 0.f;
        embl[i] = (_Float16)v;
    }

    // ---- startup: fused input weights into LDS ----
    // W_f[j][m] = sum_k W_ih[j,k]*W_proj[k,m]; b_f = b_ih + W_ih*b_proj.
    // W_proj/b_proj indices are tid-independent -> wave-uniform scalar loads.
    if (tid < 192) {
        const int j = tid;
        float wf[21];
        #pragma unroll
        for (int m = 0; m < 21; m++) wf[m] = 0.f;
        float bf = b_ih[j];
        for (int k = 0; k < 32; k++) {
            const float w = W_ih[j * 32 + k];
            bf += w * b_proj[k];
            #pragma unroll
            for (int m = 0; m < 21; m++) wf[m] += w * W_proj[k * 21 + m];
        }
        // fold log2e (r,z rows) / 2log2e (n rows): activations = raw exp2
        const float s = (j < 128) ? LOG2E : 2.f * LOG2E;
        #pragma unroll
        for (int m = 0; m < 21; m++) A.wfs[j][m] = wf[m] * s;
        #pragma unroll
        for (int m = 21; m < 32; m++) A.wfs[j][m] = 0.f;
        bfs[j] = bf;
    }
    __syncthreads();

    // ---- extract per-lane A-fragments + biases (registers) ----
    // A-layout: A[m=lane&15][k=(lane>>4)*8+pos]
    half8 Af[3], Ah[3][2];
    {
        const int m16 = l & 15, kq = l >> 4;
        #pragma unroll
        for (int g3 = 0; g3 < 3; g3++) {
            const int jr = g3 * 64 + wv * 16 + m16;
            _Float16 v[8];
            #pragma unroll
            for (int m = 0; m < 8; m++) v[m] = (_Float16)A.wfs[jr][kq * 8 + m];
            Af[g3] = *(half8*)v;
            const float s = (g3 < 2) ? LOG2E : 2.f * LOG2E;
            #pragma unroll
            for (int kt = 0; kt < 2; kt++) {
                _Float16 w[8];
                #pragma unroll
                for (int m = 0; m < 8; m++)
                    w[m] = (_Float16)(W_hh[jr * HID + kt * 32 + kq * 8 + m] * s);
                Ah[g3][kt] = *(half8*)w;
            }
        }
    }
    f32x4 biasR, biasZ, biasX, biasH;
    #pragma unroll
    for (int e = 0; e < 4; e++) {
        const int idx = 16 * wv + 4 * q + e;
        biasR[e] = (bfs[idx]      + b_hh[idx])      * LOG2E;
        biasZ[e] = (bfs[64 + idx] + b_hh[64 + idx]) * LOG2E;
        biasX[e] = bfs[128 + idx]  * (2.f * LOG2E);
        biasH[e] = b_hh[128 + idx] * (2.f * LOG2E);
    }
    __syncthreads();   // wfs dead; arena becomes pb/hb/part

    // ---- stage pb (+ mask popcount partials), zero hb ----
    for (int i = tid; i < 2 * 16 * 72 / 2; i += 256) ((int*)A.c.hb)[i] = 0;
    {
        const int r = tid >> 4, tl = tid & 15;
        const int base = (g * 16 + r) * TT;
        int cnt = 0;
        #pragma unroll
        for (int i = 0; i < 8; i++) {
            const int t = tl + 16 * i;
            const int a = actor_ids[base + t], c = action_ids[base + t];
            const int s = street_ids[base + t];
            const _Float16 f16 = (_Float16)bet[base + t];
            const unsigned fb = (unsigned)*(const unsigned short*)&f16;
            A.c.pb[t][r] = (int)(a | (c << 3) | (s << 5) | (fb << 16));
            cnt += (mask[base + t] != 0);
        }
        A.c.part[r][tl] = cnt;
    }
    __syncthreads();
    if (tid < 16) {
        int L = 0;
        #pragma unroll
        for (int i = 0; i < 16; i++) L += A.c.part[tid][i];
        A.c.Lsh[tid] = L;
    }
    __syncthreads();

    const int Ln = A.c.Lsh[n];
    int Lmax = Ln;     // butterfly max over the 16 n-columns (wave-uniform)
    #pragma unroll
    for (int k = 1; k < 16; k <<= 1) {
        const int o = __shfl_xor(Lmax, k);
        Lmax = (o > Lmax) ? o : Lmax;
    }

    const bool isq2 = (q == 2);
    const int sh = (q == 1) ? 3 : (q == 2) ? 5 : 0;
    const int mk = (q == 1) ? 3 : (q == 3) ? 0 : 7;
    const int of = (q == 1) ? 7 : (q == 2) ? 11 : (q == 3) ? 16 : 0;

    float h[4] = {0.f, 0.f, 0.f, 0.f};

    // prime step-0 x-side accumulators
    f32x4 xR, xZ, xX;
    {
        const int p = A.c.pb[0][n];
        const int eidx = ((p >> sh) & mk) + of;
        half8 Bf = *(const half8*)&embl[eidx * 8];
        uint4* bu = (uint4*)&Bf;
        bu->z = isq2 ? ((unsigned)p >> 16) : bu->z;   // {bet16, 0} at k=20,21
        xR = __builtin_amdgcn_mfma_f32_16x16x32_f16(Af[0], Bf, biasR, 0, 0, 0);
        xZ = __builtin_amdgcn_mfma_f32_16x16x32_f16(Af[1], Bf, biasZ, 0, 0, 0);
        xX = __builtin_amdgcn_mfma_f32_16x16x32_f16(Af[2], Bf, biasX, 0, 0, 0);
    }

    for (int t = 0; t < Lmax; t++) {
        const int buf = t & 1;
        const half8 Bh0 = *(const half8*)&A.c.hb[buf][n][q * 8];
        const half8 Bh1 = *(const half8*)&A.c.hb[buf][n][32 + q * 8];
        // K-tiles chained through the C operand (3 independent depth-2 chains)
        f32x4 aR = __builtin_amdgcn_mfma_f32_16x16x32_f16(Ah[0][0], Bh0, xR, 0, 0, 0);
        aR = __builtin_amdgcn_mfma_f32_16x16x32_f16(Ah[0][1], Bh1, aR, 0, 0, 0);
        f32x4 aZ = __builtin_amdgcn_mfma_f32_16x16x32_f16(Ah[1][0], Bh0, xZ, 0, 0, 0);
        aZ = __builtin_amdgcn_mfma_f32_16x16x32_f16(Ah[1][1], Bh1, aZ, 0, 0, 0);
        f32x4 aH = __builtin_amdgcn_mfma_f32_16x16x32_f16(Ah[2][0], Bh0, biasH, 0, 0, 0);
        aH = __builtin_amdgcn_mfma_f32_16x16x32_f16(Ah[2][1], Bh1, aH, 0, 0, 0);
        const f32x4 aXc = xX;

        // prefetch step t+1 x-side (independent of this step's h)
        {
            const int tn = (t + 1 < TT) ? t + 1 : TT - 1;
            const int p = A.c.pb[tn][n];
            const int eidx = ((p >> sh) & mk) + of;
            half8 Bf = *(const half8*)&embl[eidx * 8];
            uint4* bu = (uint4*)&Bf;
            bu->z = isq2 ? ((unsigned)p >> 16) : bu->z;
            xR = __builtin_amdgcn_mfma_f32_16x16x32_f16(Af[0], Bf, biasR, 0, 0, 0);
            xZ = __builtin_amdgcn_mfma_f32_16x16x32_f16(Af[1], Bf, biasZ, 0, 0, 0);
            xX = __builtin_amdgcn_mfma_f32_16x16x32_f16(Af[2], Bf, biasX, 0, 0, 0);
        }

        const bool live = (t < Ln);
        _Float16 hp[4];
        #pragma unroll
        for (int e = 0; e < 4; e++) {
            // weights pre-scaled: aR,aZ in log2 domain; aX,aH in 2log2e domain
            const float r = __builtin_amdgcn_rcpf(1.f + __builtin_amdgcn_exp2f(-aR[e]));
            const float z = __builtin_amdgcn_rcpf(1.f + __builtin_amdgcn_exp2f(-aZ[e]));
            const float y2 = aXc[e] + r * aH[e];           // = 2*log2e*y
            const float nn = 1.f - 2.f * __builtin_amdgcn_rcpf(1.f + __builtin_amdgcn_exp2f(y2));
            const float hv = nn + z * (h[e] - nn);
            h[e] = live ? hv : h[e];
            hp[e] = (_Float16)h[e];
        }
        *(uint2*)&A.c.hb[buf ^ 1][n][16 * wv + 4 * q] = *(uint2*)hp;
        __syncthreads();
    }

    float4 o = make_float4(h[0], h[1], h[2], h[3]);
    *(float4*)&out[(g * 16 + n) * HID + 16 * wv + 4 * q] = o;
}

extern "C" void kernel_launch(void* const* d_in, const int* in_sizes, int n_in,
                              void* d_out, int out_size, void* d_ws, size_t ws_size,
                              hipStream_t stream) {
    const int*   actor_ids  = (const int*)d_in[0];
    const int*   action_ids = (const int*)d_in[1];
    const int*   street_ids = (const int*)d_in[2];
    const float* bet        = (const float*)d_in[3];
    const int*   vmask      = (const int*)d_in[4];
    const float* E_actor    = (const float*)d_in[5];
    const float* E_action   = (const float*)d_in[6];
    const float* E_street   = (const float*)d_in[7];
    const float* W_proj     = (const float*)d_in[8];
    const float* b_proj     = (const float*)d_in[9];
    const float* W_ih       = (const float*)d_in[10];
    const float* W_hh       = (const float*)d_in[11];
    const float* b_ih       = (const float*)d_in[12];
    const float* b_hh       = (const float*)d_in[13];
    float*       out        = (float*)d_out;

    gru_fused<<<NGRP, 256, 0, stream>>>(actor_ids, action_ids, street_ids, bet,
                                        vmask, E_actor, E_action, E_street,
                                        W_proj, b_proj, W_ih, b_ih, W_hh, b_hh,
                                        out);
}